// Round 6
// baseline (2777.134 us; speedup 1.0000x reference)
//
#include <hip/hip_runtime.h>
#include <hip/hip_bf16.h>

typedef unsigned short u16;
typedef unsigned int   u32;
typedef __attribute__((ext_vector_type(8))) short short8;   // 8 bf16 (4 VGPRs)
typedef __attribute__((ext_vector_type(4))) float f32x4;

#define BBt 128
#define SS 128
#define RR 32
#define NEx 3
#define MB (1024 * 1024)

static __device__ __forceinline__ float bs2f(u16 u){ return __uint_as_float(((u32)u) << 16); }
static __device__ __forceinline__ u16 f2bs(float x){
    u32 u = __float_as_uint(x);
    u += 0x7fff + ((u >> 16) & 1);          // RNE
    return (u16)(u >> 16);
}
static __device__ __forceinline__ float ldany(const float* p){ return *p; }
static __device__ __forceinline__ float ldany(const u16* p){ return bs2f(*p); }

// ===========================================================================
// MFMA GEMM: C[M,N] = A[M,K] @ W[K,N] (+bias) (+Res).
// BM=128, BN=128 (cols >= Ncols masked), BK=32, 256 threads (4 waves 2x2).
// A: fp32 or bf16. W: fp32 row-major (transposed to LDS). C: fp32 or bf16.
// M % 128 == 0 (grid covers), K % 32 == 0, Ncols % 8 == 0. Batched via z.
// ===========================================================================
template<typename TA, typename TRes, typename TC>
__global__ __launch_bounds__(256) void gemm_mfma(
    const TA* __restrict__ A, int lda, long long sA,
    const float* __restrict__ W, int ldw, long long sW,
    const float* __restrict__ bias,
    const TRes* __restrict__ Res, int ldr,
    TC* __restrict__ C, int ldc, long long sC,
    int K, int Ncols)
{
    int bz = blockIdx.z;
    A += (long long)bz * sA;
    W += (long long)bz * sW;
    C += (long long)bz * sC;

    __shared__ __align__(16) u16 As[128][40];   // [m][k]
    __shared__ __align__(16) u16 Bs[128][40];   // [n][k] (W transposed)

    int tid = threadIdx.x;
    long long row0 = (long long)blockIdx.y * 128;
    int col0 = blockIdx.x * 128;

    int wid = tid >> 6, lane = tid & 63;
    int wm = (wid >> 1) * 64, wn = (wid & 1) * 64;
    int l15 = lane & 15, quad = lane >> 4;

    f32x4 acc[4][4];
    #pragma unroll
    for (int i = 0; i < 4; ++i)
        #pragma unroll
        for (int j = 0; j < 4; ++j)
            acc[i][j] = (f32x4){0.f, 0.f, 0.f, 0.f};

    int ar = tid >> 1, ak = (tid & 1) * 16;
    int bk0 = (tid & 15) * 2, bn0 = (tid >> 4) * 8;

    for (int kt = 0; kt < K; kt += 32) {
        {   // ---- stage A tile [128,32] -> bf16 ----
            const TA* src = A + (row0 + ar) * lda + kt + ak;
            if constexpr (sizeof(TA) == 4) {
                u16 tmp[16];
                #pragma unroll
                for (int t = 0; t < 16; t += 4) {
                    float4 f = *(const float4*)(src + t);
                    tmp[t] = f2bs(f.x); tmp[t+1] = f2bs(f.y);
                    tmp[t+2] = f2bs(f.z); tmp[t+3] = f2bs(f.w);
                }
                *(uint4*)&As[ar][ak]     = *(const uint4*)&tmp[0];
                *(uint4*)&As[ar][ak + 8] = *(const uint4*)&tmp[8];
            } else {
                *(uint4*)&As[ar][ak]     = *(const uint4*)(src);
                *(uint4*)&As[ar][ak + 8] = *(const uint4*)(src + 8);
            }
        }
        {   // ---- stage W tile [32,128] transposed -> Bs[n][k], N-guarded ----
            if (col0 + bn0 < Ncols) {
                const float* w0 = W + (long long)(kt + bk0) * ldw + col0 + bn0;
                const float* w1 = w0 + ldw;
                float r0[8], r1[8];
                *(float4*)&r0[0] = *(const float4*)(w0);
                *(float4*)&r0[4] = *(const float4*)(w0 + 4);
                *(float4*)&r1[0] = *(const float4*)(w1);
                *(float4*)&r1[4] = *(const float4*)(w1 + 4);
                #pragma unroll
                for (int i = 0; i < 8; ++i) {
                    u32 packed = (u32)f2bs(r0[i]) | ((u32)f2bs(r1[i]) << 16);
                    *(u32*)&Bs[bn0 + i][bk0] = packed;
                }
            } else {
                #pragma unroll
                for (int i = 0; i < 8; ++i)
                    *(u32*)&Bs[bn0 + i][bk0] = 0u;
            }
        }
        __syncthreads();

        short8 af[4], bfr[4];
        #pragma unroll
        for (int mt = 0; mt < 4; ++mt)
            af[mt] = *(const short8*)&As[wm + mt * 16 + l15][quad * 8];
        #pragma unroll
        for (int nt = 0; nt < 4; ++nt)
            bfr[nt] = *(const short8*)&Bs[wn + nt * 16 + l15][quad * 8];
        #pragma unroll
        for (int mt = 0; mt < 4; ++mt)
            #pragma unroll
            for (int nt = 0; nt < 4; ++nt)
                acc[mt][nt] = __builtin_amdgcn_mfma_f32_16x16x32_bf16(
                    af[mt], bfr[nt], acc[mt][nt], 0, 0, 0);
        __syncthreads();
    }

    // ---- epilogue: C/D layout col=lane&15, row=quad*4+reg ----
    #pragma unroll
    for (int mt = 0; mt < 4; ++mt) {
        #pragma unroll
        for (int r = 0; r < 4; ++r) {
            long long row = row0 + wm + mt * 16 + quad * 4 + r;
            #pragma unroll
            for (int nt = 0; nt < 4; ++nt) {
                int col = col0 + wn + nt * 16 + l15;
                if (col >= Ncols) continue;
                float v = acc[mt][nt][r];
                if (bias) v += bias[col];
                if (Res)  v += ldany(&Res[row * ldr + col]);
                if constexpr (sizeof(TC) == 4) C[row * ldc + col] = v;
                else                           C[row * ldc + col] = f2bs(v);
            }
        }
    }
}

// ===========================================================================
// Flash attention, bf16 in/out. Block per (head,batch), thread per query.
// out may alias Q (all global reads precede the post-barrier stores).
// ===========================================================================
__global__ __launch_bounds__(128) void attn_bf_k(
    const u16* __restrict__ Q, const u16* __restrict__ K,
    const u16* __restrict__ V, u16* __restrict__ out,
    int L, int causal)
{
    int h = blockIdx.x, b = blockIdx.y;
    int tid = threadIdx.x;
    __shared__ __align__(16) u16 kS[128][64];
    __shared__ __align__(16) u16 vS[128][64];

    for (int r = tid; r < L; r += 128) {
        const uint4* ks = (const uint4*)&K[((long long)b * L + r) * 512 + h * 64];
        const uint4* vs = (const uint4*)&V[((long long)b * L + r) * 512 + h * 64];
        uint4* kd = (uint4*)&kS[r][0];
        uint4* vd = (uint4*)&vS[r][0];
        #pragma unroll
        for (int t = 0; t < 8; ++t) { kd[t] = ks[t]; vd[t] = vs[t]; }
    }
    float q[64];
    {
        const u32* qp = (const u32*)&Q[((long long)b * 128 + tid) * 512 + h * 64];
        #pragma unroll
        for (int t = 0; t < 32; ++t) {
            u32 u = qp[t];
            q[2*t]   = __uint_as_float(u << 16) * 0.125f;
            q[2*t+1] = __uint_as_float(u & 0xffff0000u) * 0.125f;
        }
    }
    __syncthreads();

    int jmax = causal ? tid : (L - 1);
    float m = -1e30f, l = 0.f;
    float acc[64];
    #pragma unroll
    for (int d = 0; d < 64; ++d) acc[d] = 0.f;

    for (int j = 0; j <= jmax; ++j) {
        const uint4* kr = (const uint4*)&kS[j][0];
        float s = 0.f;
        #pragma unroll
        for (int t = 0; t < 8; ++t) {
            uint4 u4 = kr[t];
            u32 uu[4] = {u4.x, u4.y, u4.z, u4.w};
            #pragma unroll
            for (int e = 0; e < 4; ++e) {
                int d = t * 8 + e * 2;
                s = fmaf(q[d],   __uint_as_float(uu[e] << 16), s);
                s = fmaf(q[d+1], __uint_as_float(uu[e] & 0xffff0000u), s);
            }
        }
        float mn = fmaxf(m, s);
        float corr = __expf(m - mn);
        float p = __expf(s - mn);
        l = l * corr + p;
        const uint4* vr = (const uint4*)&vS[j][0];
        #pragma unroll
        for (int t = 0; t < 8; ++t) {
            uint4 u4 = vr[t];
            u32 uu[4] = {u4.x, u4.y, u4.z, u4.w};
            #pragma unroll
            for (int e = 0; e < 4; ++e) {
                int d = t * 8 + e * 2;
                acc[d]   = fmaf(p, __uint_as_float(uu[e] << 16),        acc[d]   * corr);
                acc[d+1] = fmaf(p, __uint_as_float(uu[e] & 0xffff0000u), acc[d+1] * corr);
            }
        }
        m = mn;
    }
    float inv = 1.f / l;
    u32 ou[32];
    #pragma unroll
    for (int t = 0; t < 32; ++t)
        ou[t] = (u32)f2bs(acc[2*t] * inv) | ((u32)f2bs(acc[2*t+1] * inv) << 16);
    uint4* op = (uint4*)&out[((long long)b * 128 + tid) * 512 + h * 64];
    #pragma unroll
    for (int t = 0; t < 8; ++t) op[t] = *(const uint4*)&ou[t * 4];
}

// ===========================================================================
// LayerNorm over 512, templated dtypes. In-place OK.
// ===========================================================================
template<typename TI, typename TO>
__global__ __launch_bounds__(256) void ln512_t(
    const TI* __restrict__ x, const float* __restrict__ g,
    const float* __restrict__ bt, TO* __restrict__ y, float eps)
{
    int row = blockIdx.x, tid = threadIdx.x;
    long long base = (long long)row * 512;
    float v0 = ldany(&x[base + tid]);
    float v1 = ldany(&x[base + 256 + tid]);
    float s = v0 + v1, ss = v0 * v0 + v1 * v1;
    #pragma unroll
    for (int o = 32; o >= 1; o >>= 1) { s += __shfl_xor(s, o); ss += __shfl_xor(ss, o); }
    __shared__ float red[2][4];
    int wave = tid >> 6, lane = tid & 63;
    if (lane == 0) { red[0][wave] = s; red[1][wave] = ss; }
    __syncthreads();
    s  = red[0][0] + red[0][1] + red[0][2] + red[0][3];
    ss = red[1][0] + red[1][1] + red[1][2] + red[1][3];
    float mean = s * (1.f / 512.f);
    float var = ss * (1.f / 512.f) - mean * mean;
    float rstd = rsqrtf(fmaxf(var, 0.f) + eps);
    float o0 = (v0 - mean) * rstd * g[tid]       + bt[tid];
    float o1 = (v1 - mean) * rstd * g[256 + tid] + bt[256 + tid];
    if constexpr (sizeof(TO) == 4) { y[base + tid] = o0; y[base + 256 + tid] = o1; }
    else { y[base + tid] = f2bs(o0); y[base + 256 + tid] = f2bs(o1); }
}

// ===========================================================================
// MoE expert block v2: grid (B, 8 s-chunks) = 1024 blocks, 16 tokens each
// (4 waves x 4). K/V staged bf16 (LDS ~29 KB -> ~4 blocks/CU).
// ===========================================================================
__global__ __launch_bounds__(256) void moe_expert2_k(
    const float* __restrict__ xs,     // [B*S,64]
    const float* __restrict__ ke,     // [3, B*R, 64]
    const float* __restrict__ ve,
    const float* __restrict__ Wq,     // [3,64,64]
    const float* __restrict__ Wo,     // [3,64,64]
    const float* __restrict__ Wg,     // [64,3]
    const float* __restrict__ bg,     // [3]
    float* __restrict__ priori)       // [B*S,64]
{
    int b = blockIdx.x;
    int s0 = blockIdx.y * 16;
    int tid = threadIdx.x;
    int wave = tid >> 6, lane = tid & 63;

    __shared__ u16 kS[NEx][RR][66];
    __shared__ u16 vS[NEx][RR][66];
    __shared__ float xrow[4][64];
    __shared__ float qS[4][64];
    __shared__ float eoS[4][64];
    __shared__ float pS[4][RR];

    for (int idx = tid; idx < NEx * RR * 64; idx += 256) {
        int e = idx >> 11;
        int rd = idx & 2047;
        int r = rd >> 6, d = rd & 63;
        long long g = (long long)e * (BBt * RR * 64) + (long long)b * (RR * 64) + rd;
        kS[e][r][d] = f2bs(ke[g]);
        vS[e][r][d] = f2bs(ve[g]);
    }
    __syncthreads();

    #pragma unroll
    for (int i = 0; i < 4; ++i) {
        int s = s0 + wave + 4 * i;
        long long row = (long long)b * SS + s;
        xrow[wave][lane] = xs[row * 64 + lane];
        __syncthreads();

        float l0 = bg[0], l1 = bg[1], l2 = bg[2];
        for (int j = 0; j < 64; ++j) {
            float xj = xrow[wave][j];
            l0 = fmaf(xj, Wg[j * 3 + 0], l0);
            l1 = fmaf(xj, Wg[j * 3 + 1], l1);
            l2 = fmaf(xj, Wg[j * 3 + 2], l2);
        }
        float mg = fmaxf(l0, fmaxf(l1, l2));
        float e0 = __expf(l0 - mg), e1 = __expf(l1 - mg), e2 = __expf(l2 - mg);
        float ginv = 1.f / (e0 + e1 + e2);
        float gate[3] = {e0 * ginv, e1 * ginv, e2 * ginv};

        float pri = 0.f;
        #pragma unroll
        for (int e = 0; e < NEx; ++e) {
            float q = 0.f;
            for (int j = 0; j < 64; ++j)
                q = fmaf(xrow[wave][j], Wq[e * 4096 + j * 64 + lane], q);
            qS[wave][lane] = q;
            __syncthreads();

            float sc;
            if (lane < RR) {
                float t = 0.f;
                for (int j = 0; j < 64; ++j)
                    t = fmaf(qS[wave][j], bs2f(kS[e][lane][j]), t);
                sc = t * 0.125f;   // 1/sqrt(64)
            } else sc = -1e30f;
            float mx = sc;
            #pragma unroll
            for (int o = 16; o >= 1; o >>= 1) mx = fmaxf(mx, __shfl_xor(mx, o));
            float ex = __expf(sc - mx);
            float sm = ex;
            #pragma unroll
            for (int o = 16; o >= 1; o >>= 1) sm += __shfl_xor(sm, o);
            if (lane < RR) pS[wave][lane] = ex / sm;
            __syncthreads();

            float eo = 0.f;
            #pragma unroll
            for (int r = 0; r < RR; ++r)
                eo = fmaf(pS[wave][r], bs2f(vS[e][r][lane]), eo);
            eoS[wave][lane] = eo;
            __syncthreads();

            float o = 0.f;
            for (int j = 0; j < 64; ++j)
                o = fmaf(eoS[wave][j], Wo[e * 4096 + j * 64 + lane], o);
            pri = fmaf(gate[e], o, pri);
            __syncthreads();
        }
        priori[row * 64 + lane] = pri;
    }
}

// ===========================================================================
// Small causal MHA on 64-dim priori (H=8, dh=8, S=128). qkv packed [B*S,192].
// ===========================================================================
__global__ __launch_bounds__(128) void attn_small_k(
    const float* __restrict__ qkv, float* __restrict__ out)
{
    int h = blockIdx.x, b = blockIdx.y;
    int tid = threadIdx.x;
    __shared__ float kS[SS][9], vS[SS][9];
    long long base = ((long long)b * SS + tid) * 192;
    #pragma unroll
    for (int d = 0; d < 8; ++d) {
        kS[tid][d] = qkv[base + 64 + h * 8 + d];
        vS[tid][d] = qkv[base + 128 + h * 8 + d];
    }
    float q[8];
    #pragma unroll
    for (int d = 0; d < 8; ++d)
        q[d] = qkv[base + h * 8 + d] * 0.35355339059327373f;
    __syncthreads();

    float m = -1e30f, l = 0.f, acc[8] = {};
    for (int j = 0; j <= tid; ++j) {
        float s = 0.f;
        #pragma unroll
        for (int d = 0; d < 8; ++d) s = fmaf(q[d], kS[j][d], s);
        float mn = fmaxf(m, s);
        float corr = __expf(m - mn);
        float p = __expf(s - mn);
        l = l * corr + p;
        #pragma unroll
        for (int d = 0; d < 8; ++d) acc[d] = fmaf(p, vS[j][d], acc[d] * corr);
        m = mn;
    }
    float inv = 1.f / l;
    #pragma unroll
    for (int d = 0; d < 8; ++d)
        out[((long long)b * SS + tid) * 64 + h * 8 + d] = acc[d] * inv;
}

__global__ __launch_bounds__(256) void ln64_k(
    const float* __restrict__ x, const float* __restrict__ g,
    const float* __restrict__ bt, float* __restrict__ y, int M)
{
    int wave = threadIdx.x >> 6, lane = threadIdx.x & 63;
    int row = blockIdx.x * 4 + wave;
    if (row >= M) return;
    long long base = (long long)row * 64;
    float v = x[base + lane];
    float s = v, ss = v * v;
    #pragma unroll
    for (int o = 32; o >= 1; o >>= 1) { s += __shfl_xor(s, o); ss += __shfl_xor(ss, o); }
    float mean = s * (1.f / 64.f);
    float var = ss * (1.f / 64.f) - mean * mean;
    float rstd = rsqrtf(fmaxf(var, 0.f) + 1e-5f);
    y[base + lane] = (v - mean) * rstd * g[lane] + bt[lane];
}

// ===========================================================================
extern "C" void kernel_launch(void* const* d_in, const int* in_sizes, int n_in,
                              void* d_out, int out_size, void* d_ws, size_t ws_size,
                              hipStream_t stream)
{
    (void)in_sizes; (void)n_in; (void)out_size; (void)ws_size;
    const float* hidden = (const float*)d_in[0];
    const float* tag    = (const float*)d_in[1];
    const float* feats  = (const float*)d_in[2];
    const float* refs   = (const float*)d_in[3];
    const float* W_moe  = (const float*)d_in[4];
    const float* b_moe  = (const float*)d_in[5];
    const float* Wg     = (const float*)d_in[6];
    const float* bg     = (const float*)d_in[7];
    const float* Wq_e   = (const float*)d_in[8];
    const float* Wk_e   = (const float*)d_in[9];
    const float* Wv_e   = (const float*)d_in[10];
    const float* Wo_e   = (const float*)d_in[11];
    const float* g_np   = (const float*)d_in[12];
    const float* b_np   = (const float*)d_in[13];
    const float* Wi_p   = (const float*)d_in[14];
    const float* bi_p   = (const float*)d_in[15];
    const float* Wo_p   = (const float*)d_in[16];
    const float* bo_p   = (const float*)d_in[17];
    const float* W_pe   = (const float*)d_in[18];
    const float* b_pe   = (const float*)d_in[19];
    const float* g_nh   = (const float*)d_in[20];
    const float* b_nh   = (const float*)d_in[21];
    const float* Wi_f   = (const float*)d_in[22];
    const float* bi_f   = (const float*)d_in[23];
    const float* Wo_f   = (const float*)d_in[24];
    const float* bo_f   = (const float*)d_in[25];
    const float* g_nfh  = (const float*)d_in[26];
    const float* b_nfh  = (const float*)d_in[27];
    const float* Wq_a   = (const float*)d_in[28];
    const float* bq_a   = (const float*)d_in[29];
    const float* Wk_a   = (const float*)d_in[30];
    const float* bk_a   = (const float*)d_in[31];
    const float* Wv_a   = (const float*)d_in[32];
    const float* bv_a   = (const float*)d_in[33];
    const float* Wd     = (const float*)d_in[34];
    const float* bd     = (const float*)d_in[35];
    const float* g_ln   = (const float*)d_in[36];
    const float* b_ln   = (const float*)d_in[37];
    float* out = (float*)d_out;
    char* ob = (char*)d_out;
    char* wb = (char*)d_ws;

    // bf16 slabs: ws = W0|W1 (16 MiB each); d_out doubles as O0|O1.
    u16* W0 = (u16*)(wb + 0LL * 16 * MB);
    u16* W1 = (u16*)(wb + 1LL * 16 * MB);
    u16* O0 = (u16*)(ob + 0LL * 16 * MB);
    u16* O1 = (u16*)(ob + 1LL * 16 * MB);

    // Stage A/B fp32 scratch inside d_out (lifetime-disjoint with O0/O1 use):
    float* o_xs   = (float*)(ob + 0LL  * MB);
    float* o_ke   = (float*)(ob + 4LL  * MB);
    float* o_ve   = (float*)(ob + 7LL  * MB);
    float* o_pri  = (float*)(ob + 10LL * MB);
    float* o_np64 = (float*)(ob + 14LL * MB);
    float* o_qkv  = (float*)(ob + 18LL * MB);
    float* o_attp = (float*)(ob + 0LL  * MB);
    float* o_tmp  = (float*)(ob + 4LL  * MB);

    dim3 blk(256);
    const float* fnull = nullptr;

    // ---- A: MoE priori ----
    gemm_mfma<float, float, float><<<dim3(1, 128), blk, 0, stream>>>(     // xs
        tag, 512, 0, W_moe, 64, 0, b_moe, fnull, 0, o_xs, 64, 0, 512, 64);
    gemm_mfma<float, float, float><<<dim3(1, 32, 3), blk, 0, stream>>>(   // k_e
        refs, 512, 4096LL * 512, Wk_e, 64, 512LL * 64, nullptr, fnull, 0,
        o_ke, 64, 4096LL * 64, 512, 64);
    gemm_mfma<float, float, float><<<dim3(1, 32, 3), blk, 0, stream>>>(   // v_e
        refs, 512, 4096LL * 512, Wv_e, 64, 512LL * 64, nullptr, fnull, 0,
        o_ve, 64, 4096LL * 64, 512, 64);
    moe_expert2_k<<<dim3(128, 8), blk, 0, stream>>>(o_xs, o_ke, o_ve, Wq_e, Wo_e, Wg, bg, o_pri);

    // ---- B: priori causal self-MHA + expansion to 512 ----
    ln64_k<<<dim3(4096), blk, 0, stream>>>(o_pri, g_np, b_np, o_np64, 16384);
    gemm_mfma<float, float, float><<<dim3(2, 128), blk, 0, stream>>>(     // qkv_p
        o_np64, 64, 0, Wi_p, 192, 0, bi_p, fnull, 0, o_qkv, 192, 0, 64, 192);
    attn_small_k<<<dim3(8, 128), dim3(128), 0, stream>>>(o_qkv, o_attp);
    gemm_mfma<float, float, float><<<dim3(1, 128), blk, 0, stream>>>(     // tmp64
        o_attp, 64, 0, Wo_p, 64, 0, bo_p, o_pri, 64, o_tmp, 64, 0, 64, 64);
    gemm_mfma<float, float, u16><<<dim3(4, 128), blk, 0, stream>>>(       // priori_e -> W0
        o_tmp, 64, 0, W_pe, 512, 0, b_pe, fnull, 0, W0, 512, 0, 64, 512);

    // ---- C: fusion cross-MHA ----
    ln512_t<u16, u16><<<dim3(16384), blk, 0, stream>>>(W0, g_nh, b_nh, W0, 1e-5f); // npri
    gemm_mfma<u16, float, u16><<<dim3(4, 128), blk, 0, stream>>>(                   // Kf -> O1
        W0, 512, 0, Wi_f + 512, 1536, 0, bi_f + 512, fnull, 0, O1, 512, 0, 512, 512);
    gemm_mfma<u16, float, u16><<<dim3(4, 128), blk, 0, stream>>>(                   // Vf -> W1
        W0, 512, 0, Wi_f + 1024, 1536, 0, bi_f + 1024, fnull, 0, W1, 512, 0, 512, 512);
    gemm_mfma<float, float, u16><<<dim3(4, 128), blk, 0, stream>>>(                 // Qf -> O0
        hidden, 512, 0, Wi_f, 1536, 0, bi_f, fnull, 0, O0, 512, 0, 512, 512);
    attn_bf_k<<<dim3(8, 128), dim3(128), 0, stream>>>(O0, O1, W1, W0, 128, 1);      // attn -> W0
    gemm_mfma<u16, float, u16><<<dim3(4, 128), blk, 0, stream>>>(                   // hidden2 -> O0
        W0, 512, 0, Wo_f, 512, 0, bo_f, hidden, 512, O0, 512, 0, 512, 512);

    // ---- D: feat cross-attention ----
    ln512_t<u16, u16><<<dim3(16384), blk, 0, stream>>>(O0, g_nfh, b_nfh, O0, 1e-5f); // nh
    gemm_mfma<u16, float, u16><<<dim3(4, 128), blk, 0, stream>>>(                    // q_a -> O1
        O0, 512, 0, Wq_a, 512, 0, bq_a, fnull, 0, O1, 512, 0, 512, 512);
    gemm_mfma<float, float, u16><<<dim3(4, 84), blk, 0, stream>>>(                   // k_a -> W0
        feats, 512, 0, Wk_a, 512, 0, bk_a, fnull, 0, W0, 512, 0, 512, 512);
    gemm_mfma<float, float, u16><<<dim3(4, 84), blk, 0, stream>>>(                   // v_a -> W1
        feats, 512, 0, Wv_a, 512, 0, bv_a, fnull, 0, W1, 512, 0, 512, 512);
    attn_bf_k<<<dim3(8, 128), dim3(128), 0, stream>>>(O1, W0, W1, O1, 84, 0);        // ctx in-place
    gemm_mfma<u16, u16, u16><<<dim3(4, 128), blk, 0, stream>>>(                      // ctxd -> W0
        O1, 512, 0, Wd, 512, 0, bd, O0, 512, W0, 512, 0, 512, 512);

    // ---- E: final post-LN (eps=1e-12) -> fp32 d_out ----
    ln512_t<u16, float><<<dim3(16384), blk, 0, stream>>>(W0, g_ln, b_ln, out, 1e-12f);
}

// Round 7
// 1323.755 us; speedup vs baseline: 2.0979x; 2.0979x over previous
//
#include <hip/hip_runtime.h>
#include <hip/hip_bf16.h>

typedef unsigned short u16;
typedef unsigned int   u32;
typedef __attribute__((ext_vector_type(8))) short short8;   // 8 bf16 (4 VGPRs)
typedef __attribute__((ext_vector_type(4))) float f32x4;

#define BBt 128
#define SS 128
#define RR 32
#define NEx 3
#define MB (1024 * 1024)

static __device__ __forceinline__ float bs2f(u16 u){ return __uint_as_float(((u32)u) << 16); }
static __device__ __forceinline__ u16 f2bs(float x){
    u32 u = __float_as_uint(x);
    u += 0x7fff + ((u >> 16) & 1);          // RNE
    return (u16)(u >> 16);
}
static __device__ __forceinline__ float ldany(const float* p){ return *p; }
static __device__ __forceinline__ float ldany(const u16* p){ return bs2f(*p); }

// ===========================================================================
// MFMA GEMM: C[M,N] = A[M,K] @ W[K,N] (+bias) (+Res).
// BM=128, BN=128 (cols >= Ncols masked), BK=32, 256 threads (4 waves 2x2).
// A: fp32 or bf16. W: fp32 row-major (transposed to LDS). C: fp32 or bf16.
// M % 128 == 0 (grid covers), K % 32 == 0, Ncols % 8 == 0. Batched via z.
// ===========================================================================
template<typename TA, typename TRes, typename TC>
__global__ __launch_bounds__(256) void gemm_mfma(
    const TA* __restrict__ A, int lda, long long sA,
    const float* __restrict__ W, int ldw, long long sW,
    const float* __restrict__ bias,
    const TRes* __restrict__ Res, int ldr,
    TC* __restrict__ C, int ldc, long long sC,
    int K, int Ncols)
{
    int bz = blockIdx.z;
    A += (long long)bz * sA;
    W += (long long)bz * sW;
    C += (long long)bz * sC;

    __shared__ __align__(16) u16 As[128][40];   // [m][k]
    __shared__ __align__(16) u16 Bs[128][40];   // [n][k] (W transposed)

    int tid = threadIdx.x;
    long long row0 = (long long)blockIdx.y * 128;
    int col0 = blockIdx.x * 128;

    int wid = tid >> 6, lane = tid & 63;
    int wm = (wid >> 1) * 64, wn = (wid & 1) * 64;
    int l15 = lane & 15, quad = lane >> 4;

    f32x4 acc[4][4];
    #pragma unroll
    for (int i = 0; i < 4; ++i)
        #pragma unroll
        for (int j = 0; j < 4; ++j)
            acc[i][j] = (f32x4){0.f, 0.f, 0.f, 0.f};

    int ar = tid >> 1, ak = (tid & 1) * 16;
    int bk0 = (tid & 15) * 2, bn0 = (tid >> 4) * 8;

    for (int kt = 0; kt < K; kt += 32) {
        {   // ---- stage A tile [128,32] -> bf16 ----
            const TA* src = A + (row0 + ar) * lda + kt + ak;
            if constexpr (sizeof(TA) == 4) {
                u16 tmp[16];
                #pragma unroll
                for (int t = 0; t < 16; t += 4) {
                    float4 f = *(const float4*)(src + t);
                    tmp[t] = f2bs(f.x); tmp[t+1] = f2bs(f.y);
                    tmp[t+2] = f2bs(f.z); tmp[t+3] = f2bs(f.w);
                }
                *(uint4*)&As[ar][ak]     = *(const uint4*)&tmp[0];
                *(uint4*)&As[ar][ak + 8] = *(const uint4*)&tmp[8];
            } else {
                *(uint4*)&As[ar][ak]     = *(const uint4*)(src);
                *(uint4*)&As[ar][ak + 8] = *(const uint4*)(src + 8);
            }
        }
        {   // ---- stage W tile [32,128] transposed -> Bs[n][k], N-guarded ----
            if (col0 + bn0 < Ncols) {
                const float* w0 = W + (long long)(kt + bk0) * ldw + col0 + bn0;
                const float* w1 = w0 + ldw;
                float r0[8], r1[8];
                *(float4*)&r0[0] = *(const float4*)(w0);
                *(float4*)&r0[4] = *(const float4*)(w0 + 4);
                *(float4*)&r1[0] = *(const float4*)(w1);
                *(float4*)&r1[4] = *(const float4*)(w1 + 4);
                #pragma unroll
                for (int i = 0; i < 8; ++i) {
                    u32 packed = (u32)f2bs(r0[i]) | ((u32)f2bs(r1[i]) << 16);
                    *(u32*)&Bs[bn0 + i][bk0] = packed;
                }
            } else {
                #pragma unroll
                for (int i = 0; i < 8; ++i)
                    *(u32*)&Bs[bn0 + i][bk0] = 0u;
            }
        }
        __syncthreads();

        short8 af[4], bfr[4];
        #pragma unroll
        for (int mt = 0; mt < 4; ++mt)
            af[mt] = *(const short8*)&As[wm + mt * 16 + l15][quad * 8];
        #pragma unroll
        for (int nt = 0; nt < 4; ++nt)
            bfr[nt] = *(const short8*)&Bs[wn + nt * 16 + l15][quad * 8];
        #pragma unroll
        for (int mt = 0; mt < 4; ++mt)
            #pragma unroll
            for (int nt = 0; nt < 4; ++nt)
                acc[mt][nt] = __builtin_amdgcn_mfma_f32_16x16x32_bf16(
                    af[mt], bfr[nt], acc[mt][nt], 0, 0, 0);
        __syncthreads();
    }

    // ---- epilogue: C/D layout col=lane&15, row=quad*4+reg ----
    #pragma unroll
    for (int mt = 0; mt < 4; ++mt) {
        #pragma unroll
        for (int r = 0; r < 4; ++r) {
            long long row = row0 + wm + mt * 16 + quad * 4 + r;
            #pragma unroll
            for (int nt = 0; nt < 4; ++nt) {
                int col = col0 + wn + nt * 16 + l15;
                if (col >= Ncols) continue;
                float v = acc[mt][nt][r];
                if (bias) v += bias[col];
                if (Res)  v += ldany(&Res[row * ldr + col]);
                if constexpr (sizeof(TC) == 4) C[row * ldc + col] = v;
                else                           C[row * ldc + col] = f2bs(v);
            }
        }
    }
}

// ===========================================================================
// Flash attention, bf16 in/out. Block per (head,batch), thread per query.
// out may alias Q (all global reads precede the post-barrier stores).
// ===========================================================================
__global__ __launch_bounds__(128) void attn_bf_k(
    const u16* __restrict__ Q, const u16* __restrict__ K,
    const u16* __restrict__ V, u16* __restrict__ out,
    int L, int causal)
{
    int h = blockIdx.x, b = blockIdx.y;
    int tid = threadIdx.x;
    __shared__ __align__(16) u16 kS[128][64];
    __shared__ __align__(16) u16 vS[128][64];

    for (int r = tid; r < L; r += 128) {
        const uint4* ks = (const uint4*)&K[((long long)b * L + r) * 512 + h * 64];
        const uint4* vs = (const uint4*)&V[((long long)b * L + r) * 512 + h * 64];
        uint4* kd = (uint4*)&kS[r][0];
        uint4* vd = (uint4*)&vS[r][0];
        #pragma unroll
        for (int t = 0; t < 8; ++t) { kd[t] = ks[t]; vd[t] = vs[t]; }
    }
    float q[64];
    {
        const u32* qp = (const u32*)&Q[((long long)b * 128 + tid) * 512 + h * 64];
        #pragma unroll
        for (int t = 0; t < 32; ++t) {
            u32 u = qp[t];
            q[2*t]   = __uint_as_float(u << 16) * 0.125f;
            q[2*t+1] = __uint_as_float(u & 0xffff0000u) * 0.125f;
        }
    }
    __syncthreads();

    int jmax = causal ? tid : (L - 1);
    float m = -1e30f, l = 0.f;
    float acc[64];
    #pragma unroll
    for (int d = 0; d < 64; ++d) acc[d] = 0.f;

    for (int j = 0; j <= jmax; ++j) {
        const uint4* kr = (const uint4*)&kS[j][0];
        float s = 0.f;
        #pragma unroll
        for (int t = 0; t < 8; ++t) {
            uint4 u4 = kr[t];
            u32 uu[4] = {u4.x, u4.y, u4.z, u4.w};
            #pragma unroll
            for (int e = 0; e < 4; ++e) {
                int d = t * 8 + e * 2;
                s = fmaf(q[d],   __uint_as_float(uu[e] << 16), s);
                s = fmaf(q[d+1], __uint_as_float(uu[e] & 0xffff0000u), s);
            }
        }
        float mn = fmaxf(m, s);
        float corr = __expf(m - mn);
        float p = __expf(s - mn);
        l = l * corr + p;
        const uint4* vr = (const uint4*)&vS[j][0];
        #pragma unroll
        for (int t = 0; t < 8; ++t) {
            uint4 u4 = vr[t];
            u32 uu[4] = {u4.x, u4.y, u4.z, u4.w};
            #pragma unroll
            for (int e = 0; e < 4; ++e) {
                int d = t * 8 + e * 2;
                acc[d]   = fmaf(p, __uint_as_float(uu[e] << 16),        acc[d]   * corr);
                acc[d+1] = fmaf(p, __uint_as_float(uu[e] & 0xffff0000u), acc[d+1] * corr);
            }
        }
        m = mn;
    }
    float inv = 1.f / l;
    u32 ou[32];
    #pragma unroll
    for (int t = 0; t < 32; ++t)
        ou[t] = (u32)f2bs(acc[2*t] * inv) | ((u32)f2bs(acc[2*t+1] * inv) << 16);
    uint4* op = (uint4*)&out[((long long)b * 128 + tid) * 512 + h * 64];
    #pragma unroll
    for (int t = 0; t < 8; ++t) op[t] = *(const uint4*)&ou[t * 4];
}

// ===========================================================================
// LayerNorm over 512, templated dtypes. In-place OK.
// ===========================================================================
template<typename TI, typename TO>
__global__ __launch_bounds__(256) void ln512_t(
    const TI* __restrict__ x, const float* __restrict__ g,
    const float* __restrict__ bt, TO* __restrict__ y, float eps)
{
    int row = blockIdx.x, tid = threadIdx.x;
    long long base = (long long)row * 512;
    float v0 = ldany(&x[base + tid]);
    float v1 = ldany(&x[base + 256 + tid]);
    float s = v0 + v1, ss = v0 * v0 + v1 * v1;
    #pragma unroll
    for (int o = 32; o >= 1; o >>= 1) { s += __shfl_xor(s, o); ss += __shfl_xor(ss, o); }
    __shared__ float red[2][4];
    int wave = tid >> 6, lane = tid & 63;
    if (lane == 0) { red[0][wave] = s; red[1][wave] = ss; }
    __syncthreads();
    s  = red[0][0] + red[0][1] + red[0][2] + red[0][3];
    ss = red[1][0] + red[1][1] + red[1][2] + red[1][3];
    float mean = s * (1.f / 512.f);
    float var = ss * (1.f / 512.f) - mean * mean;
    float rstd = rsqrtf(fmaxf(var, 0.f) + eps);
    float o0 = (v0 - mean) * rstd * g[tid]       + bt[tid];
    float o1 = (v1 - mean) * rstd * g[256 + tid] + bt[256 + tid];
    if constexpr (sizeof(TO) == 4) { y[base + tid] = o0; y[base + 256 + tid] = o1; }
    else { y[base + tid] = f2bs(o0); y[base + 256 + tid] = f2bs(o1); }
}

// ===========================================================================
// MoE expert block v3: v1's dynamic-loop body (no unroll => no VGPR spill)
// with v2's 8x grid: (B, 8 s-chunks) = 1024 blocks, 16 tokens each.
// K/V staged bf16 (LDS ~29 KB).
// ===========================================================================
__global__ __launch_bounds__(256) void moe_expert3_k(
    const float* __restrict__ xs,     // [B*S,64]
    const float* __restrict__ ke,     // [3, B*R, 64]
    const float* __restrict__ ve,
    const float* __restrict__ Wq,     // [3,64,64]
    const float* __restrict__ Wo,     // [3,64,64]
    const float* __restrict__ Wg,     // [64,3]
    const float* __restrict__ bg,     // [3]
    float* __restrict__ priori)       // [B*S,64]
{
    int b = blockIdx.x;
    int s0 = blockIdx.y * 16;
    int tid = threadIdx.x;
    int wave = tid >> 6, lane = tid & 63;

    __shared__ u16 kS[NEx][RR][66];
    __shared__ u16 vS[NEx][RR][66];
    __shared__ float xrow[4][64];
    __shared__ float qS[4][64];
    __shared__ float eoS[4][64];
    __shared__ float pS[4][RR];

    for (int idx = tid; idx < NEx * RR * 64; idx += 256) {
        int e = idx >> 11;
        int rd = idx & 2047;
        int r = rd >> 6, d = rd & 63;
        long long g = (long long)e * (BBt * RR * 64) + (long long)b * (RR * 64) + rd;
        kS[e][r][d] = f2bs(ke[g]);
        vS[e][r][d] = f2bs(ve[g]);
    }
    __syncthreads();

    for (int s = s0 + wave; s < s0 + 16; s += 4) {
        long long row = (long long)b * SS + s;
        xrow[wave][lane] = xs[row * 64 + lane];
        __syncthreads();

        float l0 = bg[0], l1 = bg[1], l2 = bg[2];
        for (int j = 0; j < 64; ++j) {
            float xj = xrow[wave][j];
            l0 = fmaf(xj, Wg[j * 3 + 0], l0);
            l1 = fmaf(xj, Wg[j * 3 + 1], l1);
            l2 = fmaf(xj, Wg[j * 3 + 2], l2);
        }
        float mg = fmaxf(l0, fmaxf(l1, l2));
        float e0 = __expf(l0 - mg), e1 = __expf(l1 - mg), e2 = __expf(l2 - mg);
        float ginv = 1.f / (e0 + e1 + e2);
        float gate[3] = {e0 * ginv, e1 * ginv, e2 * ginv};

        float pri = 0.f;
        #pragma unroll
        for (int e = 0; e < NEx; ++e) {
            float q = 0.f;
            for (int j = 0; j < 64; ++j)
                q = fmaf(xrow[wave][j], Wq[e * 4096 + j * 64 + lane], q);
            qS[wave][lane] = q;
            __syncthreads();

            float sc;
            if (lane < RR) {
                float t = 0.f;
                for (int j = 0; j < 64; ++j)
                    t = fmaf(qS[wave][j], bs2f(kS[e][lane][j]), t);
                sc = t * 0.125f;   // 1/sqrt(64)
            } else sc = -1e30f;
            float mx = sc;
            #pragma unroll
            for (int o = 16; o >= 1; o >>= 1) mx = fmaxf(mx, __shfl_xor(mx, o));
            float ex = __expf(sc - mx);
            float sm = ex;
            #pragma unroll
            for (int o = 16; o >= 1; o >>= 1) sm += __shfl_xor(sm, o);
            if (lane < RR) pS[wave][lane] = ex / sm;
            __syncthreads();

            float eo = 0.f;
            #pragma unroll
            for (int r = 0; r < RR; ++r)
                eo = fmaf(pS[wave][r], bs2f(vS[e][r][lane]), eo);
            eoS[wave][lane] = eo;
            __syncthreads();

            float o = 0.f;
            for (int j = 0; j < 64; ++j)
                o = fmaf(eoS[wave][j], Wo[e * 4096 + j * 64 + lane], o);
            pri = fmaf(gate[e], o, pri);
            __syncthreads();
        }
        priori[row * 64 + lane] = pri;
    }
}

// ===========================================================================
// Small causal MHA on 64-dim priori (H=8, dh=8, S=128). qkv packed [B*S,192].
// ===========================================================================
__global__ __launch_bounds__(128) void attn_small_k(
    const float* __restrict__ qkv, float* __restrict__ out)
{
    int h = blockIdx.x, b = blockIdx.y;
    int tid = threadIdx.x;
    __shared__ float kS[SS][9], vS[SS][9];
    long long base = ((long long)b * SS + tid) * 192;
    #pragma unroll
    for (int d = 0; d < 8; ++d) {
        kS[tid][d] = qkv[base + 64 + h * 8 + d];
        vS[tid][d] = qkv[base + 128 + h * 8 + d];
    }
    float q[8];
    #pragma unroll
    for (int d = 0; d < 8; ++d)
        q[d] = qkv[base + h * 8 + d] * 0.35355339059327373f;
    __syncthreads();

    float m = -1e30f, l = 0.f, acc[8] = {};
    for (int j = 0; j <= tid; ++j) {
        float s = 0.f;
        #pragma unroll
        for (int d = 0; d < 8; ++d) s = fmaf(q[d], kS[j][d], s);
        float mn = fmaxf(m, s);
        float corr = __expf(m - mn);
        float p = __expf(s - mn);
        l = l * corr + p;
        #pragma unroll
        for (int d = 0; d < 8; ++d) acc[d] = fmaf(p, vS[j][d], acc[d] * corr);
        m = mn;
    }
    float inv = 1.f / l;
    #pragma unroll
    for (int d = 0; d < 8; ++d)
        out[((long long)b * SS + tid) * 64 + h * 8 + d] = acc[d] * inv;
}

__global__ __launch_bounds__(256) void ln64_k(
    const float* __restrict__ x, const float* __restrict__ g,
    const float* __restrict__ bt, float* __restrict__ y, int M)
{
    int wave = threadIdx.x >> 6, lane = threadIdx.x & 63;
    int row = blockIdx.x * 4 + wave;
    if (row >= M) return;
    long long base = (long long)row * 64;
    float v = x[base + lane];
    float s = v, ss = v * v;
    #pragma unroll
    for (int o = 32; o >= 1; o >>= 1) { s += __shfl_xor(s, o); ss += __shfl_xor(ss, o); }
    float mean = s * (1.f / 64.f);
    float var = ss * (1.f / 64.f) - mean * mean;
    float rstd = rsqrtf(fmaxf(var, 0.f) + 1e-5f);
    y[base + lane] = (v - mean) * rstd * g[lane] + bt[lane];
}

// ===========================================================================
extern "C" void kernel_launch(void* const* d_in, const int* in_sizes, int n_in,
                              void* d_out, int out_size, void* d_ws, size_t ws_size,
                              hipStream_t stream)
{
    (void)in_sizes; (void)n_in; (void)out_size; (void)ws_size;
    const float* hidden = (const float*)d_in[0];
    const float* tag    = (const float*)d_in[1];
    const float* feats  = (const float*)d_in[2];
    const float* refs   = (const float*)d_in[3];
    const float* W_moe  = (const float*)d_in[4];
    const float* b_moe  = (const float*)d_in[5];
    const float* Wg     = (const float*)d_in[6];
    const float* bg     = (const float*)d_in[7];
    const float* Wq_e   = (const float*)d_in[8];
    const float* Wk_e   = (const float*)d_in[9];
    const float* Wv_e   = (const float*)d_in[10];
    const float* Wo_e   = (const float*)d_in[11];
    const float* g_np   = (const float*)d_in[12];
    const float* b_np   = (const float*)d_in[13];
    const float* Wi_p   = (const float*)d_in[14];
    const float* bi_p   = (const float*)d_in[15];
    const float* Wo_p   = (const float*)d_in[16];
    const float* bo_p   = (const float*)d_in[17];
    const float* W_pe   = (const float*)d_in[18];
    const float* b_pe   = (const float*)d_in[19];
    const float* g_nh   = (const float*)d_in[20];
    const float* b_nh   = (const float*)d_in[21];
    const float* Wi_f   = (const float*)d_in[22];
    const float* bi_f   = (const float*)d_in[23];
    const float* Wo_f   = (const float*)d_in[24];
    const float* bo_f   = (const float*)d_in[25];
    const float* g_nfh  = (const float*)d_in[26];
    const float* b_nfh  = (const float*)d_in[27];
    const float* Wq_a   = (const float*)d_in[28];
    const float* bq_a   = (const float*)d_in[29];
    const float* Wk_a   = (const float*)d_in[30];
    const float* bk_a   = (const float*)d_in[31];
    const float* Wv_a   = (const float*)d_in[32];
    const float* bv_a   = (const float*)d_in[33];
    const float* Wd     = (const float*)d_in[34];
    const float* bd     = (const float*)d_in[35];
    const float* g_ln   = (const float*)d_in[36];
    const float* b_ln   = (const float*)d_in[37];
    float* out = (float*)d_out;
    char* ob = (char*)d_out;
    char* wb = (char*)d_ws;

    // bf16 slabs: ws = W0|W1 (16 MiB each); d_out doubles as O0|O1.
    u16* W0 = (u16*)(wb + 0LL * 16 * MB);
    u16* W1 = (u16*)(wb + 1LL * 16 * MB);
    u16* O0 = (u16*)(ob + 0LL * 16 * MB);
    u16* O1 = (u16*)(ob + 1LL * 16 * MB);

    // Stage A/B fp32 scratch inside d_out (lifetime-disjoint with O0/O1 use):
    float* o_xs   = (float*)(ob + 0LL  * MB);
    float* o_ke   = (float*)(ob + 4LL  * MB);
    float* o_ve   = (float*)(ob + 7LL  * MB);
    float* o_pri  = (float*)(ob + 10LL * MB);
    float* o_np64 = (float*)(ob + 14LL * MB);
    float* o_qkv  = (float*)(ob + 18LL * MB);
    float* o_attp = (float*)(ob + 0LL  * MB);
    float* o_tmp  = (float*)(ob + 4LL  * MB);

    dim3 blk(256);
    const float* fnull = nullptr;

    // ---- A: MoE priori ----
    gemm_mfma<float, float, float><<<dim3(1, 128), blk, 0, stream>>>(     // xs
        tag, 512, 0, W_moe, 64, 0, b_moe, fnull, 0, o_xs, 64, 0, 512, 64);
    gemm_mfma<float, float, float><<<dim3(1, 32, 3), blk, 0, stream>>>(   // k_e
        refs, 512, 4096LL * 512, Wk_e, 64, 512LL * 64, nullptr, fnull, 0,
        o_ke, 64, 4096LL * 64, 512, 64);
    gemm_mfma<float, float, float><<<dim3(1, 32, 3), blk, 0, stream>>>(   // v_e
        refs, 512, 4096LL * 512, Wv_e, 64, 512LL * 64, nullptr, fnull, 0,
        o_ve, 64, 4096LL * 64, 512, 64);
    moe_expert3_k<<<dim3(128, 8), blk, 0, stream>>>(o_xs, o_ke, o_ve, Wq_e, Wo_e, Wg, bg, o_pri);

    // ---- B: priori causal self-MHA + expansion to 512 ----
    ln64_k<<<dim3(4096), blk, 0, stream>>>(o_pri, g_np, b_np, o_np64, 16384);
    gemm_mfma<float, float, float><<<dim3(2, 128), blk, 0, stream>>>(     // qkv_p
        o_np64, 64, 0, Wi_p, 192, 0, bi_p, fnull, 0, o_qkv, 192, 0, 64, 192);
    attn_small_k<<<dim3(8, 128), dim3(128), 0, stream>>>(o_qkv, o_attp);
    gemm_mfma<float, float, float><<<dim3(1, 128), blk, 0, stream>>>(     // tmp64
        o_attp, 64, 0, Wo_p, 64, 0, bo_p, o_pri, 64, o_tmp, 64, 0, 64, 64);
    gemm_mfma<float, float, u16><<<dim3(4, 128), blk, 0, stream>>>(       // priori_e -> W0
        o_tmp, 64, 0, W_pe, 512, 0, b_pe, fnull, 0, W0, 512, 0, 64, 512);

    // ---- C: fusion cross-MHA ----
    ln512_t<u16, u16><<<dim3(16384), blk, 0, stream>>>(W0, g_nh, b_nh, W0, 1e-5f); // npri
    gemm_mfma<u16, float, u16><<<dim3(4, 128), blk, 0, stream>>>(                   // Kf -> O1
        W0, 512, 0, Wi_f + 512, 1536, 0, bi_f + 512, fnull, 0, O1, 512, 0, 512, 512);
    gemm_mfma<u16, float, u16><<<dim3(4, 128), blk, 0, stream>>>(                   // Vf -> W1
        W0, 512, 0, Wi_f + 1024, 1536, 0, bi_f + 1024, fnull, 0, W1, 512, 0, 512, 512);
    gemm_mfma<float, float, u16><<<dim3(4, 128), blk, 0, stream>>>(                 // Qf -> O0
        hidden, 512, 0, Wi_f, 1536, 0, bi_f, fnull, 0, O0, 512, 0, 512, 512);
    attn_bf_k<<<dim3(8, 128), dim3(128), 0, stream>>>(O0, O1, W1, W0, 128, 1);      // attn -> W0
    gemm_mfma<u16, float, u16><<<dim3(4, 128), blk, 0, stream>>>(                   // hidden2 -> O0
        W0, 512, 0, Wo_f, 512, 0, bo_f, hidden, 512, O0, 512, 0, 512, 512);

    // ---- D: feat cross-attention ----
    ln512_t<u16, u16><<<dim3(16384), blk, 0, stream>>>(O0, g_nfh, b_nfh, O0, 1e-5f); // nh
    gemm_mfma<u16, float, u16><<<dim3(4, 128), blk, 0, stream>>>(                    // q_a -> O1
        O0, 512, 0, Wq_a, 512, 0, bq_a, fnull, 0, O1, 512, 0, 512, 512);
    gemm_mfma<float, float, u16><<<dim3(4, 84), blk, 0, stream>>>(                   // k_a -> W0
        feats, 512, 0, Wk_a, 512, 0, bk_a, fnull, 0, W0, 512, 0, 512, 512);
    gemm_mfma<float, float, u16><<<dim3(4, 84), blk, 0, stream>>>(                   // v_a -> W1
        feats, 512, 0, Wv_a, 512, 0, bv_a, fnull, 0, W1, 512, 0, 512, 512);
    attn_bf_k<<<dim3(8, 128), dim3(128), 0, stream>>>(O1, W0, W1, O1, 84, 0);        // ctx in-place
    gemm_mfma<u16, u16, u16><<<dim3(4, 128), blk, 0, stream>>>(                      // ctxd -> W0
        O1, 512, 0, Wd, 512, 0, bd, O0, 512, W0, 512, 0, 512, 512);

    // ---- E: final post-LN (eps=1e-12) -> fp32 d_out ----
    ln512_t<u16, float><<<dim3(16384), blk, 0, stream>>>(W0, g_ln, b_ln, out, 1e-12f);
}